// Round 3
// baseline (486.294 us; speedup 1.0000x reference)
//
#include <hip/hip_runtime.h>
#include <hip/hip_bf16.h>

#define B_      64
#define S_      4096
#define DIM_    256
#define DA_     64
#define NEG_    (-1e30f)
#define CHUNKS_ 16
#define ROWS_   256           // seq rows per chunk (4 tiles x 64)
#define PSTR_   260           // partial stride: m, l, pad, pad, o[256] (16B-aligned o)

typedef _Float16 half8 __attribute__((ext_vector_type(8)));
typedef float float4v __attribute__((ext_vector_type(4)));

// tanh(x) = 1 - 2/(exp(2x)+1); exact at +/-inf; err ~1e-6 << 2e-3 tol.
__device__ __forceinline__ float tanh_fast(float x) {
    float e = __expf(2.0f * x);
    return 1.0f - 2.0f * __builtin_amdgcn_rcpf(e + 1.0f);
}

// Kernel 0 (unchanged): A (DIM x DA fp32) -> fp16 swizzled into MFMA A-fragment
// order; detect mask encoding (flag=1 => int32 elements, flag=0 => 1-byte).
// at_sw index: ((nt*8+kb)*64 + lane)*8 + j = a[d][n],
//   d = kb*32 + (lane>>4)*8 + j, n = nt*16 + (lane&15)
__global__ __launch_bounds__(256) void prep_kernel(
    const float* __restrict__ a, const void* __restrict__ mask,
    _Float16* __restrict__ at_sw, int* __restrict__ flag)
{
    int idx = blockIdx.x * 256 + threadIdx.x;   // 0..16383
    int j    = idx & 7;
    int lane = (idx >> 3) & 63;
    int kbnt = idx >> 9;
    int kb   = kbnt & 7;
    int nt   = kbnt >> 3;
    int d  = kb * 32 + (lane >> 4) * 8 + j;
    int kf = nt * 16 + (lane & 15);
    at_sw[idx] = (_Float16)a[d * DA_ + kf];

    if (blockIdx.x == 0) {
        __shared__ int anynz;
        if (threadIdx.x == 0) anynz = 0;
        __syncthreads();
        const unsigned char* mb = (const unsigned char*)mask;
        int base = threadIdx.x * 4;   // scan first 1024 bytes
        int v = mb[base + 1] | mb[base + 2] | mb[base + 3];
        if (v) atomicOr(&anynz, 1);
        __syncthreads();
        if (threadIdx.x == 0) *flag = (anynz == 0) ? 1 : 0;
    }
}

// R7 fused kernel: zero-LDS-for-h register dataflow.
// R6 post-mortem: 133 KiB LDS -> 1 wave/SIMD -> every latency exposed (mask
// load stall, shfl chains, ds chains, vmcnt(0) drain); ~2.1 TB/s effective.
// Fix: the MFMA B-fragment is lane-row-aligned, so each lane global-loads
// exactly the 64 floats it consumes (16x float4, 100% 128B-line utilization).
// h never touches LDS; accumulation reuses the same registers. LDS = 36 KiB
// (a-frags + reduce scratch) -> VGPR-limited 2 waves/SIMD (8 waves/CU) at
// launch_bounds(256,2). Compiler pipelines pure-register loads under compute.
// Masks prefetched into 4 named scalars (rule #20: no runtime-indexed arrays).
__global__ __launch_bounds__(256, 2) void fused_kernel(
    const float* __restrict__ h, const _Float16* __restrict__ at_sw,
    const float* __restrict__ bvec, const void* __restrict__ mask,
    const int* __restrict__ flag, float* __restrict__ part)
{
    __shared__ _Float16 asw[16384];      // 32 KiB a-fragments
    __shared__ float red[4 * 256];       // per-wave write-staging (wave-private)

    const int t    = threadIdx.x;
    const int wave = t >> 6;
    const int lane = t & 63;
    const int quad = lane >> 4;
    const int nrow = lane & 15;
    const bool int32enc = (*flag != 0);

    {   // stage a-fragments (L2-hot from prep)
        const uint4* g = (const uint4*)at_sw;
        uint4* l = (uint4*)asw;
        #pragma unroll
        for (int i = 0; i < 8; ++i) l[i * 256 + t] = g[i * 256 + t];
    }

    float4 bq[4];
    #pragma unroll
    for (int nt = 0; nt < 4; ++nt)
        bq[nt] = *(const float4*)(bvec + nt * 16 + quad * 4);

    const int cg = blockIdx.x;           // chunk id, 0..1023
    const int b  = cg >> 4;
    const int c  = cg & 15;
    const long long row0 = (long long)b * S_ + c * ROWS_ + wave * 16 + nrow;
    const float* hrow = h + row0 * DIM_ + quad * 8;

    // prefetch all 4 tile masks up front (kills the per-tile mask stall)
    int mv0, mv1, mv2, mv3;
    if (int32enc) {
        const int* mi = (const int*)mask + row0;
        mv0 = mi[0]; mv1 = mi[64]; mv2 = mi[128]; mv3 = mi[192];
    } else {
        const unsigned char* mb = (const unsigned char*)mask + row0;
        mv0 = mb[0]; mv1 = mb[64]; mv2 = mb[128]; mv3 = mb[192];
    }

    __syncthreads();                     // asw visible to all waves (only barrier)

    float o[64];                         // own row's 64 cols {kb*32+quad*8+j}
    #pragma unroll
    for (int i = 0; i < 64; ++i) o[i] = 0.f;
    float m_w = NEG_, l_w = 0.f;

    auto body = [&](int tile, int mv) {
        const float* hp = hrow + (size_t)tile * 64 * DIM_;

        // own-row fragment loads: 16 x float4, strided 128 B (full-line use)
        float4 hv[16];
        #pragma unroll
        for (int kb = 0; kb < 8; ++kb) {
            hv[2 * kb]     = *(const float4*)(hp + kb * 32);
            hv[2 * kb + 1] = *(const float4*)(hp + kb * 32 + 4);
        }

        // z^T[n][own row] = sum_d a[d][n] h[row][d]
        float4v accm[4];
        #pragma unroll
        for (int nt = 0; nt < 4; ++nt) accm[nt] = (float4v){0.f, 0.f, 0.f, 0.f};
        #pragma unroll
        for (int kb = 0; kb < 8; ++kb) {
            union { _Float16 hh[8]; half8 v; } pk;
            pk.hh[0] = (_Float16)hv[2 * kb].x;     pk.hh[1] = (_Float16)hv[2 * kb].y;
            pk.hh[2] = (_Float16)hv[2 * kb].z;     pk.hh[3] = (_Float16)hv[2 * kb].w;
            pk.hh[4] = (_Float16)hv[2 * kb + 1].x; pk.hh[5] = (_Float16)hv[2 * kb + 1].y;
            pk.hh[6] = (_Float16)hv[2 * kb + 1].z; pk.hh[7] = (_Float16)hv[2 * kb + 1].w;
            #pragma unroll
            for (int nt = 0; nt < 4; ++nt) {
                half8 af = *(const half8*)&asw[((nt * 8 + kb) * 64 + lane) * 8];
                accm[nt] = __builtin_amdgcn_mfma_f32_16x16x32_f16(af, pk.v, accm[nt], 0, 0, 0);
            }
        }

        // e[own row]: lane holds n = nt*16 + quad*4 + r; reduce over quads
        float p = 0.f;
        #pragma unroll
        for (int nt = 0; nt < 4; ++nt) {
            p += tanh_fast(accm[nt][0]) * bq[nt].x;
            p += tanh_fast(accm[nt][1]) * bq[nt].y;
            p += tanh_fast(accm[nt][2]) * bq[nt].z;
            p += tanh_fast(accm[nt][3]) * bq[nt].w;
        }
        p += __shfl_xor(p, 16);
        p += __shfl_xor(p, 32);

        // per-wave online softmax over its 16 rows
        float ev = mv ? NEG_ : p;
        float mx = ev;
        mx = fmaxf(mx, __shfl_xor(mx, 1));
        mx = fmaxf(mx, __shfl_xor(mx, 2));
        mx = fmaxf(mx, __shfl_xor(mx, 4));
        mx = fmaxf(mx, __shfl_xor(mx, 8));
        float m_new = fmaxf(m_w, mx);
        float rs  = __expf(m_w - m_new);     // first tile: exp(-1e30) = 0
        float w_s = __expf(ev - m_new);
        float sm = w_s;
        sm += __shfl_xor(sm, 1);
        sm += __shfl_xor(sm, 2);
        sm += __shfl_xor(sm, 4);
        sm += __shfl_xor(sm, 8);
        l_w = l_w * rs + sm;
        m_w = m_new;

        // in-register weighted accumulation of own row (fp32, static indices)
        #pragma unroll
        for (int kb = 0; kb < 8; ++kb) {
            o[kb * 8 + 0] = fmaf(w_s, hv[2 * kb].x,     o[kb * 8 + 0] * rs);
            o[kb * 8 + 1] = fmaf(w_s, hv[2 * kb].y,     o[kb * 8 + 1] * rs);
            o[kb * 8 + 2] = fmaf(w_s, hv[2 * kb].z,     o[kb * 8 + 2] * rs);
            o[kb * 8 + 3] = fmaf(w_s, hv[2 * kb].w,     o[kb * 8 + 3] * rs);
            o[kb * 8 + 4] = fmaf(w_s, hv[2 * kb + 1].x, o[kb * 8 + 4] * rs);
            o[kb * 8 + 5] = fmaf(w_s, hv[2 * kb + 1].y, o[kb * 8 + 5] * rs);
            o[kb * 8 + 6] = fmaf(w_s, hv[2 * kb + 1].z, o[kb * 8 + 6] * rs);
            o[kb * 8 + 7] = fmaf(w_s, hv[2 * kb + 1].w, o[kb * 8 + 7] * rs);
        }
    };
    body(0, mv0); body(1, mv1); body(2, mv2); body(3, mv3);

    // reduce o over the 16-lane nrow group (same quad => same cols)
    #pragma unroll
    for (int i = 0; i < 64; ++i) {
        o[i] += __shfl_xor(o[i], 1);
        o[i] += __shfl_xor(o[i], 2);
        o[i] += __shfl_xor(o[i], 4);
        o[i] += __shfl_xor(o[i], 8);
    }
    // distribute writes: lane with nrow == i>>2 writes col (i>>3)*32+quad*8+(i&7)
    // (static reg indices; wave-private red slice -> no barrier needed)
    #pragma unroll
    for (int i = 0; i < 64; ++i) {
        if ((i >> 2) == nrow)
            red[wave * 256 + (i >> 3) * 32 + quad * 8 + (i & 7)] = o[i];
    }
    float4 o4 = *(const float4*)&red[wave * 256 + lane * 4];
    float* pc = part + (size_t)(cg * 4 + wave) * PSTR_;
    *(float4*)(pc + 4 + lane * 4) = o4;   // 1040-B stride + 16 B => aligned
    if (lane == 0) { pc[0] = m_w; pc[1] = l_w; }
}

// Kernel 2: merge 64 per-wave partials (16 chunks x 4 waves) -> out[b][d]
__global__ __launch_bounds__(256) void merge_kernel(
    const float* __restrict__ part, float* __restrict__ out)
{
    const int b = blockIdx.x;
    const int t = threadIdx.x;
    const float* pb = part + (size_t)b * 64 * PSTR_;
    float M = NEG_;
    #pragma unroll
    for (int i = 0; i < 64; ++i) M = fmaxf(M, pb[i * PSTR_]);
    float L = 0.f, o = 0.f;
    #pragma unroll
    for (int i = 0; i < 64; ++i) {
        float sc = __expf(pb[i * PSTR_] - M);
        L += pb[i * PSTR_ + 1] * sc;
        o += pb[i * PSTR_ + 4 + t] * sc;
    }
    out[b * DIM_ + t] = o / L;
}

extern "C" void kernel_launch(void* const* d_in, const int* in_sizes, int n_in,
                              void* d_out, int out_size, void* d_ws, size_t ws_size,
                              hipStream_t stream) {
    const float* h    = (const float*)d_in[0];
    const void*  mask = d_in[1];
    const float* a    = (const float*)d_in[2];
    const float* bvec = (const float*)d_in[3];
    float* out = (float*)d_out;

    char* ws = (char*)d_ws;
    _Float16* at_sw = (_Float16*)ws;              // 32,768 B
    int* flag       = (int*)(ws + 32768);
    float* part     = (float*)(ws + 36864);       // 4096 partials * 260 * 4 B ~= 4.3 MiB

    prep_kernel<<<64, 256, 0, stream>>>(a, mask, at_sw, flag);
    fused_kernel<<<B_ * CHUNKS_, 256, 0, stream>>>(h, at_sw, bvec, mask, flag, part);
    merge_kernel<<<B_, 256, 0, stream>>>(part, out);
}

// Round 4
// 400.430 us; speedup vs baseline: 1.2144x; 1.2144x over previous
//
#include <hip/hip_runtime.h>
#include <hip/hip_bf16.h>

#define B_      64
#define S_      4096
#define DIM_    256
#define DA_     64
#define NEG_    (-1e30f)
#define CHUNKS_ 16
#define ROWS_   256           // seq rows per chunk (4 tiles x 64)
#define PSTR_   260           // partial stride: m, l, pad, pad, o[256]

typedef _Float16 half8 __attribute__((ext_vector_type(8)));
typedef float float4v __attribute__((ext_vector_type(4)));

// tanh(x) = 1 - 2/(exp(2x)+1); exact at +/-inf; err ~1e-6 << 2e-3 tol.
__device__ __forceinline__ float tanh_fast(float x) {
    float e = __expf(2.0f * x);
    return 1.0f - 2.0f * __builtin_amdgcn_rcpf(e + 1.0f);
}

// Kernel 0 (unchanged): A (DIM x DA fp32) -> fp16 swizzled into MFMA A-fragment
// order; detect mask encoding (flag=1 => int32 elements, flag=0 => 1-byte).
// at_sw index: ((nt*8+kb)*64 + lane)*8 + j = a[d][n],
//   d = kb*32 + (lane>>4)*8 + j, n = nt*16 + (lane&15)
__global__ __launch_bounds__(256) void prep_kernel(
    const float* __restrict__ a, const void* __restrict__ mask,
    _Float16* __restrict__ at_sw, int* __restrict__ flag)
{
    int idx = blockIdx.x * 256 + threadIdx.x;   // 0..16383
    int j    = idx & 7;
    int lane = (idx >> 3) & 63;
    int kbnt = idx >> 9;
    int kb   = kbnt & 7;
    int nt   = kbnt >> 3;
    int d  = kb * 32 + (lane >> 4) * 8 + j;
    int kf = nt * 16 + (lane & 15);
    at_sw[idx] = (_Float16)a[d * DA_ + kf];

    if (blockIdx.x == 0) {
        __shared__ int anynz;
        if (threadIdx.x == 0) anynz = 0;
        __syncthreads();
        const unsigned char* mb = (const unsigned char*)mask;
        int base = threadIdx.x * 4;   // scan first 1024 bytes
        int v = mb[base + 1] | mb[base + 2] | mb[base + 3];
        if (v) atomicOr(&anynz, 1);
        __syncthreads();
        if (threadIdx.x == 0) *flag = (anynz == 0) ? 1 : 0;
    }
}

// R8 fused kernel: two-phase-per-tile, L2-reuse, small per-thread state.
// R5/R7 post-mortem: per-lane o[64] spills no matter the launch_bounds
// (VGPR=84/128, WRITE_SIZE 122/301 MB scratch). R6 post-mortem: 133 KiB LDS
// -> 1 wave/SIMD -> latency-exposed (~2.1 TB/s).
// Fix: phase 1 = R7's register-direct logits (hv dies within the tile, no
// cross-tile big state); phase 2 = R0's coalesced accumulation (acc0..3 per
// thread) RE-READING the tile from L2 (reuse distance ~1.6 MiB << 4 MiB/XCD).
// LDS = 37 KiB (a-frags + w/ml scratch + final reduce) -> 3 blocks/CU,
// 12 waves/CU TLP. Block-level softmax, 2 barriers/tile (parity-dbuf'd w/ml).
__global__ __launch_bounds__(256, 3) void fused_kernel(
    const float* __restrict__ h, const _Float16* __restrict__ at_sw,
    const float* __restrict__ bvec, const void* __restrict__ mask,
    const int* __restrict__ flag, float* __restrict__ part)
{
    __shared__ _Float16 asw[16384];      // 32 KiB a-fragments
    __shared__ float wl[2][64];          // per-row weights, parity-dbuf
    __shared__ float mlx[2][4];          // per-wave tile max, parity-dbuf
    __shared__ float mls[2][4];          // per-wave exp-sum, parity-dbuf
    __shared__ float red[4 * 256];       // final cross-wave acc reduce

    const int t    = threadIdx.x;
    const int wave = t >> 6;
    const int lane = t & 63;
    const int quad = lane >> 4;
    const int nrow = lane & 15;
    const bool int32enc = (*flag != 0);

    {   // stage a-fragments (L2-hot from prep)
        const uint4* g = (const uint4*)at_sw;
        uint4* l = (uint4*)asw;
        #pragma unroll
        for (int i = 0; i < 8; ++i) l[i * 256 + t] = g[i * 256 + t];
    }

    float4 bq[4];
    #pragma unroll
    for (int nt = 0; nt < 4; ++nt)
        bq[nt] = *(const float4*)(bvec + nt * 16 + quad * 4);

    const int cg = blockIdx.x;           // chunk id, 0..1023
    const int b  = cg >> 4;
    const int c  = cg & 15;
    const long long crow = (long long)b * S_ + c * ROWS_;
    const long long row0 = crow + wave * 16 + nrow;   // this lane's tile-0 row
    const float* hrow = h + row0 * DIM_ + quad * 8;

    // prefetch all 4 tile masks up front (no per-tile mask stall)
    int mv0, mv1, mv2, mv3;
    if (int32enc) {
        const int* mi = (const int*)mask + row0;
        mv0 = mi[0]; mv1 = mi[64]; mv2 = mi[128]; mv3 = mi[192];
    } else {
        const unsigned char* mb = (const unsigned char*)mask + row0;
        mv0 = mb[0]; mv1 = mb[64]; mv2 = mb[128]; mv3 = mb[192];
    }

    __syncthreads();                     // asw visible

    float acc0 = 0.f, acc1 = 0.f, acc2 = 0.f, acc3 = 0.f;
    float m_b = NEG_, l_b = 0.f;         // block-uniform softmax state

    auto body = [&](int tile, int mv, int par) {
        // ---------- phase 1: logits for own row (register-direct, R7) ------
        const float* hp = hrow + (size_t)tile * 64 * DIM_;
        float4 hv[16];
        #pragma unroll
        for (int kb = 0; kb < 8; ++kb) {
            hv[2 * kb]     = *(const float4*)(hp + kb * 32);
            hv[2 * kb + 1] = *(const float4*)(hp + kb * 32 + 4);
        }
        float4v accm[4];
        #pragma unroll
        for (int nt = 0; nt < 4; ++nt) accm[nt] = (float4v){0.f, 0.f, 0.f, 0.f};
        #pragma unroll
        for (int kb = 0; kb < 8; ++kb) {
            union { _Float16 hh[8]; half8 v; } pk;
            pk.hh[0] = (_Float16)hv[2 * kb].x;     pk.hh[1] = (_Float16)hv[2 * kb].y;
            pk.hh[2] = (_Float16)hv[2 * kb].z;     pk.hh[3] = (_Float16)hv[2 * kb].w;
            pk.hh[4] = (_Float16)hv[2 * kb + 1].x; pk.hh[5] = (_Float16)hv[2 * kb + 1].y;
            pk.hh[6] = (_Float16)hv[2 * kb + 1].z; pk.hh[7] = (_Float16)hv[2 * kb + 1].w;
            #pragma unroll
            for (int nt = 0; nt < 4; ++nt) {
                half8 af = *(const half8*)&asw[((nt * 8 + kb) * 64 + lane) * 8];
                accm[nt] = __builtin_amdgcn_mfma_f32_16x16x32_f16(af, pk.v, accm[nt], 0, 0, 0);
            }
        }
        float p = 0.f;
        #pragma unroll
        for (int nt = 0; nt < 4; ++nt) {
            p += tanh_fast(accm[nt][0]) * bq[nt].x;
            p += tanh_fast(accm[nt][1]) * bq[nt].y;
            p += tanh_fast(accm[nt][2]) * bq[nt].z;
            p += tanh_fast(accm[nt][3]) * bq[nt].w;
        }
        p += __shfl_xor(p, 16);
        p += __shfl_xor(p, 32);          // p uniform across quads now

        // ---------- block-level online softmax --------------------------
        float ev = mv ? NEG_ : p;
        float mx = ev;
        mx = fmaxf(mx, __shfl_xor(mx, 1));
        mx = fmaxf(mx, __shfl_xor(mx, 2));
        mx = fmaxf(mx, __shfl_xor(mx, 4));
        mx = fmaxf(mx, __shfl_xor(mx, 8));
        if (lane == 0) mlx[par][wave] = mx;
        __syncthreads();                 // barrier A
        float mt = fmaxf(fmaxf(mlx[par][0], mlx[par][1]),
                         fmaxf(mlx[par][2], mlx[par][3]));
        float m_new = fmaxf(m_b, mt);
        float rs  = __expf(m_b - m_new);
        float w_s = __expf(ev - m_new);
        if (quad == 0) wl[par][wave * 16 + nrow] = w_s;
        float sm = w_s;
        sm += __shfl_xor(sm, 1);
        sm += __shfl_xor(sm, 2);
        sm += __shfl_xor(sm, 4);
        sm += __shfl_xor(sm, 8);
        if (lane == 0) mls[par][wave] = sm;
        __syncthreads();                 // barrier B
        l_b = l_b * rs + (mls[par][0] + mls[par][1] + mls[par][2] + mls[par][3]);
        m_b = m_new;
        acc0 *= rs; acc1 *= rs; acc2 *= rs; acc3 *= rs;

        // ---------- phase 2: coalesced L2 re-read + accumulate ------------
        // wave w reads rows {st*4+w}: 64 lanes x float4 = full 1 KiB row.
        const float* tb = h + (crow + tile * 64) * DIM_;
        #pragma unroll
        for (int st = 0; st < 16; ++st) {
            int r = st * 4 + wave;
            float wr = wl[par][r];
            float4 hvv = *(const float4*)(tb + (size_t)r * DIM_ + lane * 4);
            acc0 = fmaf(wr, hvv.x, acc0);
            acc1 = fmaf(wr, hvv.y, acc1);
            acc2 = fmaf(wr, hvv.z, acc2);
            acc3 = fmaf(wr, hvv.w, acc3);
        }
        // no trailing barrier: next tile uses the other parity buffers, and
        // barrier ordering (A' then B'') proves wl[par] is consumed before
        // any thread rewrites it at tile+2.
    };
    body(0, mv0, 0); body(1, mv1, 1); body(2, mv2, 0); body(3, mv3, 1);

    // ---- cross-wave reduce (waves hold different row-groups, same dims) ----
    red[wave * 256 + lane * 4 + 0] = acc0;
    red[wave * 256 + lane * 4 + 1] = acc1;
    red[wave * 256 + lane * 4 + 2] = acc2;
    red[wave * 256 + lane * 4 + 3] = acc3;
    __syncthreads();
    float o = red[t] + red[256 + t] + red[512 + t] + red[768 + t];
    float* pc = part + (size_t)cg * PSTR_;
    pc[4 + t] = o;
    if (t == 0) { pc[0] = m_b; pc[1] = l_b; }
}

// Kernel 2: merge 16 per-chunk partials -> out[b][d]
__global__ __launch_bounds__(256) void merge_kernel(
    const float* __restrict__ part, float* __restrict__ out)
{
    const int b = blockIdx.x;
    const int t = threadIdx.x;
    const float* pb = part + (size_t)b * CHUNKS_ * PSTR_;
    float M = NEG_;
    #pragma unroll
    for (int c = 0; c < CHUNKS_; ++c) M = fmaxf(M, pb[c * PSTR_]);
    float L = 0.f, o = 0.f;
    #pragma unroll
    for (int c = 0; c < CHUNKS_; ++c) {
        float sc = __expf(pb[c * PSTR_] - M);
        L += pb[c * PSTR_ + 1] * sc;
        o += pb[c * PSTR_ + 4 + t] * sc;
    }
    out[b * DIM_ + t] = o / L;
}

extern "C" void kernel_launch(void* const* d_in, const int* in_sizes, int n_in,
                              void* d_out, int out_size, void* d_ws, size_t ws_size,
                              hipStream_t stream) {
    const float* h    = (const float*)d_in[0];
    const void*  mask = d_in[1];
    const float* a    = (const float*)d_in[2];
    const float* bvec = (const float*)d_in[3];
    float* out = (float*)d_out;

    char* ws = (char*)d_ws;
    _Float16* at_sw = (_Float16*)ws;              // 32,768 B
    int* flag       = (int*)(ws + 32768);
    float* part     = (float*)(ws + 36864);       // 1024 * 260 * 4 B ~= 1.04 MiB

    prep_kernel<<<64, 256, 0, stream>>>(a, mask, at_sw, flag);
    fused_kernel<<<B_ * CHUNKS_, 256, 0, stream>>>(h, at_sw, bvec, mask, flag, part);
    merge_kernel<<<B_, 256, 0, stream>>>(part, out);
}